// Round 6
// baseline (329.355 us; speedup 1.0000x reference)
//
#include <hip/hip_runtime.h>
#include <hip/hip_bf16.h>

// ws layout (in bf16 elements)
#define OFF_O0   0u          // 8 x 256 x 32   (o_W0 transposed, K padded 24->32)
#define OFF_O1   65536u      // 8 x 256 x 256
#define OFF_O2   589824u
#define OFF_C0   1114112u
#define OFF_C1   1179648u
#define OFF_T0   1245184u
#define OFF_T1   1310720u
#define OFF_AL   1376256u    // a_W0[:256]  transposed
#define OFF_AR   1441792u    // a_W0[256:]  transposed
#define OFF_A1   1507328u
#define OFF_ENC  1572864u    // 8 x 4096 x 256 bf16
#define OFF_ALQ  9961472u    // a_l activations, 8 x 4096 x 256
#define OFF_ARQ  18350080u   // a_r + ab0 activations

typedef short s8v __attribute__((ext_vector_type(8)));
typedef float f4v __attribute__((ext_vector_type(4)));

__device__ __forceinline__ unsigned short f2bf(float f) {
  unsigned u = __float_as_uint(f);
  unsigned r = (u + 0x7FFFu + ((u >> 16) & 1u)) >> 16;
  return (unsigned short)r;
}
__device__ __forceinline__ float bf2f(unsigned short h) {
  return __uint_as_float(((unsigned)h) << 16);
}

// ======== BM=64, 256-thread (4-wave, wn split) GEMM helpers ==============
// LDS A tiles (when used): byte = row*512 + ((2*col) ^ ((row&7)<<4))

// bias + optional relu -> bf16 to swizzled LDS (may alias input) / global
__device__ __forceinline__ void gemm_epilogue(
    f4v acc[4][4], const float* bias, int act,
    unsigned short* outb, unsigned short* gout)
{
  int lane = threadIdx.x & 63;
  int w    = threadIdx.x >> 6;
  int lr = lane & 15, kh = lane >> 4;
  if (outb) __syncthreads();   // all waves done reading the input LDS buffer
  #pragma unroll
  for (int nt = 0; nt < 4; nt++) {
    int col = w*64 + nt*16 + lr;
    float bv = bias ? bias[col] : 0.0f;
    #pragma unroll
    for (int mt = 0; mt < 4; mt++) {
      #pragma unroll
      for (int i = 0; i < 4; i++) {
        int row = mt*16 + kh*4 + i;            // C/D: col=lane&15, row=(lane>>4)*4+reg
        float v = acc[mt][nt][i] + bv;
        if (act) v = fmaxf(v, 0.0f);
        unsigned short hh = f2bf(v);
        if (outb) {
          int bofs = (2*col) ^ ((row & 7) << 4);
          *(unsigned short*)((char*)outb + row*512 + bofs) = hh;
        }
        if (gout) gout[row*256 + col] = hh;
      }
    }
  }
  if (outb) __syncthreads();
}

// K loop, A from swizzled LDS
__device__ __forceinline__ void gemm_core(
    const unsigned short* inb, const unsigned short* __restrict__ wt,
    f4v acc[4][4])
{
  int lane = threadIdx.x & 63;
  int w    = threadIdx.x >> 6;
  int lr = lane & 15, kh = lane >> 4;
  #pragma unroll
  for (int a = 0; a < 4; a++)
    #pragma unroll
    for (int b = 0; b < 4; b++) acc[a][b] = (f4v){0.f,0.f,0.f,0.f};
  #pragma unroll
  for (int k0 = 0; k0 < 256; k0 += 32) {
    s8v bfrag[4];
    #pragma unroll
    for (int nt = 0; nt < 4; nt++)
      bfrag[nt] = *(const s8v*)(wt + (w*64 + nt*16 + lr)*256 + k0 + kh*8);
    #pragma unroll
    for (int mt = 0; mt < 4; mt++) {
      int row = mt*16 + lr;
      int bofs = (2*k0 + kh*16) ^ ((row & 7) << 4);
      s8v afrag = *(const s8v*)((const char*)inb + row*512 + bofs);
      #pragma unroll
      for (int nt = 0; nt < 4; nt++)
        acc[mt][nt] = __builtin_amdgcn_mfma_f32_16x16x32_bf16(afrag, bfrag[nt], acc[mt][nt], 0, 0, 0);
    }
  }
}

// K loop, A row-major bf16 straight from GLOBAL (no LDS, no barriers)
__device__ __forceinline__ void gemm_core_gA(
    const unsigned short* __restrict__ ga,   // [64+][256]
    const unsigned short* __restrict__ wt,
    f4v acc[4][4])
{
  int lane = threadIdx.x & 63;
  int w    = threadIdx.x >> 6;
  int lr = lane & 15, kh = lane >> 4;
  #pragma unroll
  for (int a = 0; a < 4; a++)
    #pragma unroll
    for (int b = 0; b < 4; b++) acc[a][b] = (f4v){0.f,0.f,0.f,0.f};
  #pragma unroll
  for (int k0 = 0; k0 < 256; k0 += 32) {
    s8v bfrag[4];
    #pragma unroll
    for (int nt = 0; nt < 4; nt++)
      bfrag[nt] = *(const s8v*)(wt + (w*64 + nt*16 + lr)*256 + k0 + kh*8);
    #pragma unroll
    for (int mt = 0; mt < 4; mt++) {
      s8v afrag = *(const s8v*)(ga + (mt*16 + lr)*256 + k0 + kh*8);
      #pragma unroll
      for (int nt = 0; nt < 4; nt++)
        acc[mt][nt] = __builtin_amdgcn_mfma_f32_16x16x32_bf16(afrag, bfrag[nt], acc[mt][nt], 0, 0, 0);
    }
  }
}

__device__ __forceinline__ void gemm64(
    const unsigned short* inb, const unsigned short* __restrict__ wt,
    const float* bias, int act, unsigned short* outb, unsigned short* gout)
{
  f4v acc[4][4];
  gemm_core(inb, wt, acc);
  gemm_epilogue(acc, bias, act, outb, gout);
}

// fused relu(acc+b1).w2 dot + sigmoid tail (shared by pair/pred)
__device__ __forceinline__ void dot_tail(
    f4v acc[4][4], const float* __restrict__ bias,
    const float* __restrict__ w2, float b2,
    float* __restrict__ out, int m0, int offs, float* red)
{
  int lane = threadIdx.x & 63;
  int w    = threadIdx.x >> 6;
  int lr = lane & 15, kh = lane >> 4;
  float w2v[4], bv[4];
  #pragma unroll
  for (int nt = 0; nt < 4; nt++) {
    int col = w*64 + nt*16 + lr;
    w2v[nt] = w2[col];
    bv[nt]  = bias[col];
  }
  #pragma unroll
  for (int mt = 0; mt < 4; mt++) {
    #pragma unroll
    for (int i = 0; i < 4; i++) {
      float s = 0.0f;
      #pragma unroll
      for (int nt = 0; nt < 4; nt++)
        s += fmaxf(acc[mt][nt][i] + bv[nt], 0.0f) * w2v[nt];
      s += __shfl_xor(s, 1);
      s += __shfl_xor(s, 2);
      s += __shfl_xor(s, 4);
      s += __shfl_xor(s, 8);
      if (lr == 0) red[(mt*16 + kh*4 + i)*4 + w] = s;
    }
  }
  __syncthreads();
  if (threadIdx.x < 64) {
    int row = threadIdx.x;
    float s = red[row*4] + red[row*4+1] + red[row*4+2] + red[row*4+3];
    out[(m0 + row)*80 + offs] = 1.0f / (1.0f + __expf(-s - b2));
  }
}

// layer 0: A built from fp32 x (global, row stride 24, K padded to 32)
__device__ __forceinline__ void gemm_xg(
    const float* __restrict__ xg, int m0,
    const unsigned short* __restrict__ wt, const float* bias,
    unsigned short* outb)
{
  int lane = threadIdx.x & 63;
  int w    = threadIdx.x >> 6;
  int lr = lane & 15, kh = lane >> 4;
  f4v acc[4][4];
  #pragma unroll
  for (int a = 0; a < 4; a++)
    #pragma unroll
    for (int b = 0; b < 4; b++) acc[a][b] = (f4v){0.f,0.f,0.f,0.f};

  s8v bfrag[4];
  #pragma unroll
  for (int nt = 0; nt < 4; nt++)
    bfrag[nt] = *(const s8v*)(wt + (w*64 + nt*16 + lr)*32 + kh*8);
  #pragma unroll
  for (int mt = 0; mt < 4; mt++) {
    s8v a8 = (s8v){0,0,0,0,0,0,0,0};
    if (kh < 3) {                       // k in [0,24); kh==3 is all pad
      const float* px = xg + (m0 + mt*16 + lr)*24 + kh*8;
      #pragma unroll
      for (int e = 0; e < 8; e++) a8[e] = (short)f2bf(px[e]);
    }
    #pragma unroll
    for (int nt = 0; nt < 4; nt++)
      acc[mt][nt] = __builtin_amdgcn_mfma_f32_16x16x32_bf16(a8, bfrag[nt], acc[mt][nt], 0, 0, 0);
  }
  gemm_epilogue(acc, bias, 1, outb, nullptr);
}

// ---------------- weight prep: fp32 -> bf16, transposed to [n][k] -------
__global__ __launch_bounds__(256) void prep_kernel(
    const float* __restrict__ oW0, const float* __restrict__ oW1,
    const float* __restrict__ oW2, const float* __restrict__ cW0,
    const float* __restrict__ cW1, const float* __restrict__ tW0,
    const float* __restrict__ tW1, const float* __restrict__ aW0,
    const float* __restrict__ aW1, unsigned short* __restrict__ ws)
{
  __shared__ float t[32][33];
  int b = blockIdx.x;
  if (b < 1472) {                       // 23 matrices of 256x256, 64 tiles each
    int m = b >> 6, tile = b & 63;
    const float* src; unsigned short* dst;
    if      (m < 8)  { src = oW1 + m*65536;       dst = ws + OFF_O1 + m*65536; }
    else if (m < 16) { src = oW2 + (m-8)*65536;   dst = ws + OFF_O2 + (m-8)*65536; }
    else if (m == 16){ src = cW0;                 dst = ws + OFF_C0; }
    else if (m == 17){ src = cW1;                 dst = ws + OFF_C1; }
    else if (m == 18){ src = tW0;                 dst = ws + OFF_T0; }
    else if (m == 19){ src = tW1;                 dst = ws + OFF_T1; }
    else if (m == 20){ src = aW1;                 dst = ws + OFF_A1; }
    else if (m == 21){ src = aW0;                 dst = ws + OFF_AL; }
    else             { src = aW0 + 65536;         dst = ws + OFF_AR; }
    int kt = tile & 7, nt = tile >> 3;
    int tx = threadIdx.x & 31, ty = threadIdx.x >> 5;
    #pragma unroll
    for (int r = 0; r < 4; r++) {
      int ky = ty*4 + r;
      t[ky][tx] = src[(kt*32 + ky)*256 + nt*32 + tx];
    }
    __syncthreads();
    #pragma unroll
    for (int r = 0; r < 4; r++) {
      int ny = ty*4 + r;
      dst[(nt*32 + ny)*256 + kt*32 + tx] = f2bf(t[tx][ny]);
    }
  } else {                              // o_W0: (8,24,256) -> (8,256,32) padded
    int idx = (b - 1472)*256 + threadIdx.x;
    int k = idx & 31, n2 = (idx >> 5) & 255, nb = idx >> 13;
    float v = (k < 24) ? oW0[(nb*24 + k)*256 + n2] : 0.0f;
    ws[OFF_O0 + idx] = f2bf(v);
  }
}

// ---------------- object encoders + a_l / (a_r + b0) projections ---------
// 512 blocks x 256 thr; BM=64; x read straight from global; buf in-place.
__global__ __launch_bounds__(256) void encoder_kernel(
    const float* __restrict__ x,
    const float* __restrict__ ob0, const float* __restrict__ ob1,
    const float* __restrict__ ob2, const float* __restrict__ ab0,
    unsigned short* __restrict__ ws)
{
  __shared__ unsigned short buf[64*256];   // 32 KB
  int b = blockIdx.x;
  int wsw = (b & 7)*64 + (b >> 3);     // XCD swizzle: one n per XCD
  int n  = wsw >> 6;
  int m0 = (wsw & 63) * 64;

  gemm_xg(x, m0, ws + OFF_O0 + n*8192, ob0 + n*256, buf);
  gemm64 (buf, ws + OFF_O1 + n*65536, ob1 + n*256, 1, buf, nullptr);
  gemm64 (buf, ws + OFF_O2 + n*65536, ob2 + n*256, 0, buf,
          ws + OFF_ENC + (unsigned)(n*4096 + m0)*256);
  gemm64 (buf, ws + OFF_AL, nullptr, 0, nullptr,
          ws + OFF_ALQ + (unsigned)(n*4096 + m0)*256);
  gemm64 (buf, ws + OFF_AR, ab0, 0, nullptr,                 // fold a_b0 here
          ws + OFF_ARQ + (unsigned)(n*4096 + m0)*256);
}

// ---------------- AonB pairs: no LDS tile, A built in registers ----------
// 4096 blocks x 256 thr. afrag = bf16(relu(L+R)) constructed inline from
// global reads; zero staging, zero big-LDS, barriers only for the 1KB dot.
__global__ __launch_bounds__(256) void pair_kernel(
    const unsigned short* __restrict__ ws,
    const float* __restrict__ ab1, const float* __restrict__ aW2,
    const float* __restrict__ ab2, float* __restrict__ out)
{
  __shared__ float red[256];
  int b = blockIdx.x;
  int wsw = (b & 7)*512 + (b >> 3);    // XCD-chunked: chunks group per XCD
  int chunk = wsw >> 6, pair = wsw & 63;
  int i = pair >> 3, j = pair & 7;
  int m0 = chunk * 64;
  const unsigned short* Lp = ws + OFF_ALQ + (unsigned)(i*4096 + m0)*256;
  const unsigned short* Rp = ws + OFF_ARQ + (unsigned)(j*4096 + m0)*256;
  const unsigned short* wt = ws + OFF_A1;

  int lane = threadIdx.x & 63;
  int w    = threadIdx.x >> 6;
  int lr = lane & 15, kh = lane >> 4;

  f4v acc[4][4];
  #pragma unroll
  for (int a = 0; a < 4; a++)
    #pragma unroll
    for (int c = 0; c < 4; c++) acc[a][c] = (f4v){0.f,0.f,0.f,0.f};

  #pragma unroll
  for (int k0 = 0; k0 < 256; k0 += 32) {
    s8v bfrag[4];
    #pragma unroll
    for (int nt = 0; nt < 4; nt++)
      bfrag[nt] = *(const s8v*)(wt + (w*64 + nt*16 + lr)*256 + k0 + kh*8);
    #pragma unroll
    for (int mt = 0; mt < 4; mt++) {
      int ro = (mt*16 + lr)*256 + k0 + kh*8;
      s8v l8 = *(const s8v*)(Lp + ro);
      s8v r8 = *(const s8v*)(Rp + ro);
      s8v a8;
      #pragma unroll
      for (int e = 0; e < 8; e++) {
        float v = bf2f((unsigned short)l8[e]) + bf2f((unsigned short)r8[e]);
        a8[e] = (short)f2bf(fmaxf(v, 0.0f));
      }
      #pragma unroll
      for (int nt = 0; nt < 4; nt++)
        acc[mt][nt] = __builtin_amdgcn_mfma_f32_16x16x32_bf16(a8, bfrag[nt], acc[mt][nt], 0, 0, 0);
    }
  }
  dot_tail(acc, ab1, aW2, ab2[0], out, m0, i*10 + j, red);
}

// ---------------- clear / ontable predicates -----------------------------
// 1024 blocks x 256 thr. GEMM1 A from global enc; h1 via 32KB LDS; GEMM2+dot.
__global__ __launch_bounds__(256) void pred_kernel(
    const unsigned short* __restrict__ ws,
    const float* __restrict__ cb0, const float* __restrict__ cb1,
    const float* __restrict__ cW2, const float* __restrict__ cb2,
    const float* __restrict__ tb0, const float* __restrict__ tb1,
    const float* __restrict__ tW2, const float* __restrict__ tb2,
    float* __restrict__ out)
{
  __shared__ unsigned short h1[64*256];    // 32 KB
  __shared__ float red[256];
  int b = blockIdx.x;
  int wsw = (b & 7)*128 + (b >> 3);    // XCD swizzle: (p,n) groups per XCD
  int p   = wsw >> 9;
  int n   = (wsw >> 6) & 7;
  int m0  = (wsw & 63) * 64;
  const unsigned short* encp = ws + OFF_ENC + (unsigned)(n*4096 + m0)*256;

  f4v acc[4][4];
  gemm_core_gA(encp, ws + (p ? OFF_T0 : OFF_C0), acc);
  gemm_epilogue(acc, p ? tb0 : cb0, 1, h1, nullptr);
  gemm_core(h1, ws + (p ? OFF_T1 : OFF_C1), acc);
  dot_tail(acc, p ? tb1 : cb1, p ? tW2 : cW2, p ? tb2[0] : cb2[0],
           out, m0, n*10 + 8 + p, red);
}

extern "C" void kernel_launch(void* const* d_in, const int* in_sizes, int n_in,
                              void* d_out, int out_size, void* d_ws, size_t ws_size,
                              hipStream_t stream) {
  (void)in_sizes; (void)n_in; (void)out_size; (void)ws_size;
  const float* x   = (const float*)d_in[0];
  const float* oW0 = (const float*)d_in[1];
  const float* ob0 = (const float*)d_in[2];
  const float* oW1 = (const float*)d_in[3];
  const float* ob1 = (const float*)d_in[4];
  const float* oW2 = (const float*)d_in[5];
  const float* ob2 = (const float*)d_in[6];
  const float* cW0 = (const float*)d_in[7];
  const float* cb0 = (const float*)d_in[8];
  const float* cW1 = (const float*)d_in[9];
  const float* cb1 = (const float*)d_in[10];
  const float* cW2 = (const float*)d_in[11];
  const float* cb2 = (const float*)d_in[12];
  const float* tW0 = (const float*)d_in[13];
  const float* tb0 = (const float*)d_in[14];
  const float* tW1 = (const float*)d_in[15];
  const float* tb1 = (const float*)d_in[16];
  const float* tW2 = (const float*)d_in[17];
  const float* tb2 = (const float*)d_in[18];
  const float* aW0 = (const float*)d_in[19];
  const float* ab0 = (const float*)d_in[20];
  const float* aW1 = (const float*)d_in[21];
  const float* ab1 = (const float*)d_in[22];
  const float* aW2 = (const float*)d_in[23];
  const float* ab2 = (const float*)d_in[24];
  unsigned short* ws = (unsigned short*)d_ws;
  float* out = (float*)d_out;

  hipLaunchKernelGGL(prep_kernel, dim3(1728), dim3(256), 0, stream,
                     oW0, oW1, oW2, cW0, cW1, tW0, tW1, aW0, aW1, ws);
  hipLaunchKernelGGL(encoder_kernel, dim3(512), dim3(256), 0, stream,
                     x, ob0, ob1, ob2, ab0, ws);
  hipLaunchKernelGGL(pair_kernel, dim3(4096), dim3(256), 0, stream,
                     ws, ab1, aW2, ab2, out);
  hipLaunchKernelGGL(pred_kernel, dim3(1024), dim3(256), 0, stream,
                     ws, cb0, cb1, cW2, cb2, tb0, tb1, tW2, tb2, out);
}

// Round 7
// 207.049 us; speedup vs baseline: 1.5907x; 1.5907x over previous
//
#include <hip/hip_runtime.h>
#include <hip/hip_bf16.h>

// ws layout (in bf16 elements)
#define OFF_O0   0u          // 8 x 256 x 32   (o_W0 transposed, K padded 24->32)
#define OFF_O1   65536u      // 8 x 256 x 256
#define OFF_O2   589824u
#define OFF_C0   1114112u
#define OFF_C1   1179648u
#define OFF_T0   1245184u
#define OFF_T1   1310720u
#define OFF_AL   1376256u    // a_W0[:256]  transposed
#define OFF_AR   1441792u    // a_W0[256:]  transposed
#define OFF_A1   1507328u
#define OFF_ENC  1572864u    // 8 x 4096 x 256 bf16
#define OFF_ALQ  9961472u    // a_l activations, 8 x 4096 x 256
#define OFF_ARQ  18350080u   // a_r + ab0 activations

typedef short s8v __attribute__((ext_vector_type(8)));
typedef float f4v __attribute__((ext_vector_type(4)));

__device__ __forceinline__ unsigned short f2bf(float f) {
  unsigned u = __float_as_uint(f);
  unsigned r = (u + 0x7FFFu + ((u >> 16) & 1u)) >> 16;
  return (unsigned short)r;
}
__device__ __forceinline__ float bf2f(unsigned short h) {
  return __uint_as_float(((unsigned)h) << 16);
}

// ---------- BM=64, 256-thread (4-wave) helpers (encoder / pred) ----------
__device__ __forceinline__ void gemm_epilogue(
    f4v acc[4][4], const float* bias, int act,
    unsigned short* outb, unsigned short* gout)
{
  int lane = threadIdx.x & 63;
  int w    = threadIdx.x >> 6;
  int lr = lane & 15, kh = lane >> 4;
  if (outb) __syncthreads();
  #pragma unroll
  for (int nt = 0; nt < 4; nt++) {
    int col = w*64 + nt*16 + lr;
    float bv = bias ? bias[col] : 0.0f;
    #pragma unroll
    for (int mt = 0; mt < 4; mt++) {
      #pragma unroll
      for (int i = 0; i < 4; i++) {
        int row = mt*16 + kh*4 + i;            // C/D: col=lane&15, row=(lane>>4)*4+reg
        float v = acc[mt][nt][i] + bv;
        if (act) v = fmaxf(v, 0.0f);
        unsigned short hh = f2bf(v);
        if (outb) {
          int bofs = (2*col) ^ ((row & 7) << 4);  // XOR swizzle (G4)
          *(unsigned short*)((char*)outb + row*512 + bofs) = hh;
        }
        if (gout) gout[row*256 + col] = hh;
      }
    }
  }
  if (outb) __syncthreads();
}

__device__ __forceinline__ void gemm_core(
    const unsigned short* inb, const unsigned short* __restrict__ wt,
    f4v acc[4][4])
{
  int lane = threadIdx.x & 63;
  int w    = threadIdx.x >> 6;
  int lr = lane & 15, kh = lane >> 4;
  #pragma unroll
  for (int a = 0; a < 4; a++)
    #pragma unroll
    for (int b = 0; b < 4; b++) acc[a][b] = (f4v){0.f,0.f,0.f,0.f};
  #pragma unroll
  for (int k0 = 0; k0 < 256; k0 += 32) {
    s8v bfrag[4];
    #pragma unroll
    for (int nt = 0; nt < 4; nt++)
      bfrag[nt] = *(const s8v*)(wt + (w*64 + nt*16 + lr)*256 + k0 + kh*8);
    #pragma unroll
    for (int mt = 0; mt < 4; mt++) {
      int row = mt*16 + lr;
      int bofs = (2*k0 + kh*16) ^ ((row & 7) << 4);
      s8v afrag = *(const s8v*)((const char*)inb + row*512 + bofs);
      #pragma unroll
      for (int nt = 0; nt < 4; nt++)
        acc[mt][nt] = __builtin_amdgcn_mfma_f32_16x16x32_bf16(afrag, bfrag[nt], acc[mt][nt], 0, 0, 0);
    }
  }
}

__device__ __forceinline__ void gemm64(
    const unsigned short* inb, const unsigned short* __restrict__ wt,
    const float* bias, int act, unsigned short* outb, unsigned short* gout)
{
  f4v acc[4][4];
  gemm_core(inb, wt, acc);
  gemm_epilogue(acc, bias, act, outb, gout);
}

// fused relu(acc+b1).w2 dot + sigmoid (BM=64)
__device__ __forceinline__ void dot_tail(
    f4v acc[4][4], const float* __restrict__ bias,
    const float* __restrict__ w2, float b2,
    float* __restrict__ out, int m0, int offs, float* red)
{
  int lane = threadIdx.x & 63;
  int w    = threadIdx.x >> 6;
  int lr = lane & 15, kh = lane >> 4;
  float w2v[4], bv[4];
  #pragma unroll
  for (int nt = 0; nt < 4; nt++) {
    int col = w*64 + nt*16 + lr;
    w2v[nt] = w2[col];
    bv[nt]  = bias[col];
  }
  #pragma unroll
  for (int mt = 0; mt < 4; mt++) {
    #pragma unroll
    for (int i = 0; i < 4; i++) {
      float s = 0.0f;
      #pragma unroll
      for (int nt = 0; nt < 4; nt++)
        s += fmaxf(acc[mt][nt][i] + bv[nt], 0.0f) * w2v[nt];
      s += __shfl_xor(s, 1);
      s += __shfl_xor(s, 2);
      s += __shfl_xor(s, 4);
      s += __shfl_xor(s, 8);
      if (lr == 0) red[(mt*16 + kh*4 + i)*4 + w] = s;
    }
  }
  __syncthreads();
  if (threadIdx.x < 64) {
    int row = threadIdx.x;
    float s = red[row*4] + red[row*4+1] + red[row*4+2] + red[row*4+3];
    out[(m0 + row)*80 + offs] = 1.0f / (1.0f + __expf(-s - b2));
  }
}

// layer 0: 64x32 (plain LDS) @ WT0 [256][32]; relu
__device__ __forceinline__ void gemm_x(
    const unsigned short* xb, const unsigned short* __restrict__ wt,
    const float* bias, unsigned short* outb)
{
  int lane = threadIdx.x & 63;
  int w    = threadIdx.x >> 6;
  int lr = lane & 15, kh = lane >> 4;
  f4v acc[4][4];
  #pragma unroll
  for (int a = 0; a < 4; a++)
    #pragma unroll
    for (int b = 0; b < 4; b++) acc[a][b] = (f4v){0.f,0.f,0.f,0.f};

  s8v bfrag[4];
  #pragma unroll
  for (int nt = 0; nt < 4; nt++)
    bfrag[nt] = *(const s8v*)(wt + (w*64 + nt*16 + lr)*32 + kh*8);
  #pragma unroll
  for (int mt = 0; mt < 4; mt++) {
    s8v afrag = *(const s8v*)(xb + (mt*16 + lr)*32 + kh*8);
    #pragma unroll
    for (int nt = 0; nt < 4; nt++)
      acc[mt][nt] = __builtin_amdgcn_mfma_f32_16x16x32_bf16(afrag, bfrag[nt], acc[mt][nt], 0, 0, 0);
  }
  gemm_epilogue(acc, bias, 1, outb, nullptr);
}

// ---------------- weight prep: fp32 -> bf16, transposed to [n][k] -------
__global__ __launch_bounds__(256) void prep_kernel(
    const float* __restrict__ oW0, const float* __restrict__ oW1,
    const float* __restrict__ oW2, const float* __restrict__ cW0,
    const float* __restrict__ cW1, const float* __restrict__ tW0,
    const float* __restrict__ tW1, const float* __restrict__ aW0,
    const float* __restrict__ aW1, unsigned short* __restrict__ ws)
{
  __shared__ float t[32][33];
  int b = blockIdx.x;
  if (b < 1472) {                       // 23 matrices of 256x256, 64 tiles each
    int m = b >> 6, tile = b & 63;
    const float* src; unsigned short* dst;
    if      (m < 8)  { src = oW1 + m*65536;       dst = ws + OFF_O1 + m*65536; }
    else if (m < 16) { src = oW2 + (m-8)*65536;   dst = ws + OFF_O2 + (m-8)*65536; }
    else if (m == 16){ src = cW0;                 dst = ws + OFF_C0; }
    else if (m == 17){ src = cW1;                 dst = ws + OFF_C1; }
    else if (m == 18){ src = tW0;                 dst = ws + OFF_T0; }
    else if (m == 19){ src = tW1;                 dst = ws + OFF_T1; }
    else if (m == 20){ src = aW1;                 dst = ws + OFF_A1; }
    else if (m == 21){ src = aW0;                 dst = ws + OFF_AL; }
    else             { src = aW0 + 65536;         dst = ws + OFF_AR; }
    int kt = tile & 7, nt = tile >> 3;
    int tx = threadIdx.x & 31, ty = threadIdx.x >> 5;
    #pragma unroll
    for (int r = 0; r < 4; r++) {
      int ky = ty*4 + r;
      t[ky][tx] = src[(kt*32 + ky)*256 + nt*32 + tx];
    }
    __syncthreads();
    #pragma unroll
    for (int r = 0; r < 4; r++) {
      int ny = ty*4 + r;
      dst[(nt*32 + ny)*256 + kt*32 + tx] = f2bf(t[tx][ny]);
    }
  } else {                              // o_W0: (8,24,256) -> (8,256,32) padded
    int idx = (b - 1472)*256 + threadIdx.x;
    int k = idx & 31, n2 = (idx >> 5) & 255, nb = idx >> 13;
    float v = (k < 24) ? oW0[(nb*24 + k)*256 + n2] : 0.0f;
    ws[OFF_O0 + idx] = f2bf(v);
  }
}

// ---------------- object encoders + a_l / (a_r + b0) projections ---------
__global__ __launch_bounds__(256) void encoder_kernel(
    const float* __restrict__ x,
    const float* __restrict__ ob0, const float* __restrict__ ob1,
    const float* __restrict__ ob2, const float* __restrict__ ab0,
    unsigned short* __restrict__ ws)
{
  __shared__ unsigned short buf[64*256];   // 32 KB, chained in-place
  __shared__ unsigned short xb[64*32];     // 4 KB
  int n  = blockIdx.x >> 6;
  int m0 = (blockIdx.x & 63) * 64;

  for (int t = threadIdx.x; t < 64*32; t += 256) {
    int row = t >> 5, c = t & 31;
    xb[t] = f2bf(c < 24 ? x[(m0 + row)*24 + c] : 0.0f);
  }
  __syncthreads();
  gemm_x (xb,  ws + OFF_O0 + n*8192,  ob0 + n*256, buf);
  gemm64 (buf, ws + OFF_O1 + n*65536, ob1 + n*256, 1, buf, nullptr);
  gemm64 (buf, ws + OFF_O2 + n*65536, ob2 + n*256, 0, buf,
          ws + OFF_ENC + (unsigned)(n*4096 + m0)*256);
  gemm64 (buf, ws + OFF_AL, nullptr, 0, nullptr,
          ws + OFF_ALQ + (unsigned)(n*4096 + m0)*256);
  gemm64 (buf, ws + OFF_AR, ab0, 0, nullptr,                 // fold a_b0 here
          ws + OFF_ARQ + (unsigned)(n*4096 + m0)*256);
}

// ---------------- AonB: persistent W1 in LDS, 32 items/block -------------
// 256 blocks x 256 thr. LDS = 128KB swizzled W1 + 2x16KB PH dbuf = 160 KB
// (1 block/CU; AITER precedent for 160KB/WG, m243). Per item: prefetch
// L/R(t+1) regs -> GEMM(t) all-LDS -> construct(t+1) -> fused dot.
__global__ __launch_bounds__(256) void pair_kernel(
    const unsigned short* __restrict__ ws,
    const float* __restrict__ ab1, const float* __restrict__ aW2,
    const float* __restrict__ ab2, float* __restrict__ out)
{
  __shared__ unsigned short wlds[256*256];     // 128 KB
  __shared__ unsigned short ph[2][32*256];     // 2 x 16 KB
  int b    = blockIdx.x;
  int i    = b >> 5;                // pair-left index: 8 i's
  int cset = b & 31;                // 4 chunks of 32 rows each
  int tid  = threadIdx.x;
  int lane = tid & 63, w = tid >> 6;
  int lr = lane & 15, kh = lane >> 4;

  // --- W1 -> LDS (swizzled), coalesced 512B rows ---
  {
    const unsigned short* wt = ws + OFF_A1;
    #pragma unroll
    for (int it = 0; it < 32; it++) {
      int idx = it*256 + tid;
      int row = idx >> 5, c8 = idx & 31;
      s8v v = *(const s8v*)(wt + row*256 + c8*8);
      *(s8v*)((char*)wlds + row*512 + ((c8*16) ^ ((row & 7) << 4))) = v;
    }
  }
  float w2v[4], bv[4];
  #pragma unroll
  for (int nt = 0; nt < 4; nt++) {
    int col = w*64 + nt*16 + lr;
    w2v[nt] = aW2[col];
    bv[nt]  = ab1[col];
  }
  float b2 = ab2[0];

  const unsigned short* Lbase = ws + OFF_ALQ + (unsigned)i*4096u*256u;
  const unsigned short* Rbase = ws + OFF_ARQ;

  // staging slot coords (4 per thread)
  int srow[4], sc8[4];
  #pragma unroll
  for (int q = 0; q < 4; q++) {
    int idx = q*256 + tid;
    srow[q] = idx >> 5; sc8[q] = idx & 31;
  }

  // prologue: stage item 0 (c=0, j=0) into ph[0]
  {
    const unsigned short* Lp = Lbase + (unsigned)(cset*4 + 0)*32u*256u;
    const unsigned short* Rp = Rbase + (unsigned)(cset*4 + 0)*32u*256u;
    #pragma unroll
    for (int q = 0; q < 4; q++) {
      s8v l8 = *(const s8v*)(Lp + srow[q]*256 + sc8[q]*8);
      s8v r8 = *(const s8v*)(Rp + srow[q]*256 + sc8[q]*8);
      s8v o8;
      #pragma unroll
      for (int e = 0; e < 8; e++) {
        float v = bf2f((unsigned short)l8[e]) + bf2f((unsigned short)r8[e]);
        o8[e] = (short)f2bf(fmaxf(v, 0.0f));
      }
      *(s8v*)((char*)ph[0] + srow[q]*512 + ((sc8[q]*16) ^ ((srow[q] & 7) << 4))) = o8;
    }
  }
  __syncthreads();

  int cur = 0;
  for (int t = 0; t < 32; t++) {
    int c = t >> 3, j = t & 7;
    // prefetch L/R for t+1 (loads issue now, consumed after GEMM)
    s8v Lr[4], Rr[4];
    if (t < 31) {
      int t1 = t + 1;
      int c1 = t1 >> 3, j1 = t1 & 7;
      const unsigned short* Lp = Lbase + (unsigned)(cset*4 + c1)*32u*256u;
      const unsigned short* Rp = Rbase + ((unsigned)j1*4096u + (cset*4 + c1)*32u)*256u;
      #pragma unroll
      for (int q = 0; q < 4; q++) {
        Lr[q] = *(const s8v*)(Lp + srow[q]*256 + sc8[q]*8);
        Rr[q] = *(const s8v*)(Rp + srow[q]*256 + sc8[q]*8);
      }
    }
    // GEMM(t): 32x256 @ 256x256, A and B both from LDS
    f4v acc[2][4];
    #pragma unroll
    for (int a = 0; a < 2; a++)
      #pragma unroll
      for (int cc = 0; cc < 4; cc++) acc[a][cc] = (f4v){0.f,0.f,0.f,0.f};
    const unsigned short* inb = ph[cur];
    #pragma unroll
    for (int k0 = 0; k0 < 256; k0 += 32) {
      s8v bfrag[4];
      #pragma unroll
      for (int nt = 0; nt < 4; nt++) {
        int row = w*64 + nt*16 + lr;
        int bofs = (2*k0 + kh*16) ^ ((row & 7) << 4);
        bfrag[nt] = *(const s8v*)((const char*)wlds + row*512 + bofs);
      }
      #pragma unroll
      for (int mt = 0; mt < 2; mt++) {
        int row = mt*16 + lr;
        int bofs = (2*k0 + kh*16) ^ ((row & 7) << 4);
        s8v afrag = *(const s8v*)((const char*)inb + row*512 + bofs);
        #pragma unroll
        for (int nt = 0; nt < 4; nt++)
          acc[mt][nt] = __builtin_amdgcn_mfma_f32_16x16x32_bf16(afrag, bfrag[nt], acc[mt][nt], 0, 0, 0);
      }
    }
    // construct PH(t+1) into the other half
    if (t < 31) {
      #pragma unroll
      for (int q = 0; q < 4; q++) {
        s8v o8;
        #pragma unroll
        for (int e = 0; e < 8; e++) {
          float v = bf2f((unsigned short)Lr[q][e]) + bf2f((unsigned short)Rr[q][e]);
          o8[e] = (short)f2bf(fmaxf(v, 0.0f));
        }
        *(s8v*)((char*)ph[cur ^ 1] + srow[q]*512 + ((sc8[q]*16) ^ ((srow[q] & 7) << 4))) = o8;
      }
    }
    __syncthreads();   // GEMM(t) reads done; PH(t+1) written
    // fused dot (h2 in regs), partials into consumed ph[cur]
    float* red = (float*)ph[cur];
    #pragma unroll
    for (int mt = 0; mt < 2; mt++) {
      #pragma unroll
      for (int ii = 0; ii < 4; ii++) {
        float s = 0.0f;
        #pragma unroll
        for (int nt = 0; nt < 4; nt++)
          s += fmaxf(acc[mt][nt][ii] + bv[nt], 0.0f) * w2v[nt];
        s += __shfl_xor(s, 1);
        s += __shfl_xor(s, 2);
        s += __shfl_xor(s, 4);
        s += __shfl_xor(s, 8);
        if (lr == 0) red[(mt*16 + kh*4 + ii)*4 + w] = s;
      }
    }
    __syncthreads();   // red written
    if (tid < 32) {
      float s = red[tid*4] + red[tid*4+1] + red[tid*4+2] + red[tid*4+3];
      out[((cset*4 + c)*32 + tid)*80 + i*10 + j] = 1.0f / (1.0f + __expf(-s - b2));
    }
    __syncthreads();   // red reads done before next construct overwrites
    cur ^= 1;
  }
}

// ---------------- clear / ontable predicates (round-2 form) --------------
__global__ __launch_bounds__(256) void pred_kernel(
    const unsigned short* __restrict__ ws,
    const float* __restrict__ cb0, const float* __restrict__ cb1,
    const float* __restrict__ cW2, const float* __restrict__ cb2,
    const float* __restrict__ tb0, const float* __restrict__ tb1,
    const float* __restrict__ tW2, const float* __restrict__ tb2,
    float* __restrict__ out)
{
  __shared__ unsigned short bufA[64*256];  // 32 KB
  __shared__ float red[256];
  int b  = blockIdx.x;
  int p  = b >> 9;            // 0=clear, 1=ontable
  int n  = (b >> 6) & 7;
  int m0 = (b & 63) * 64;
  const unsigned short* encp = ws + OFF_ENC + (unsigned)(n*4096 + m0)*256;
  for (int t = threadIdx.x; t < 64*32; t += 256) {
    int row = t >> 5, chunk = t & 31;
    s8v v = *(const s8v*)(encp + row*256 + chunk*8);
    int bofs = (chunk*16) ^ ((row & 7) << 4);
    *(s8v*)((char*)bufA + row*512 + bofs) = v;
  }
  __syncthreads();
  const unsigned short* W0 = ws + (p ? OFF_T0 : OFF_C0);
  const unsigned short* W1 = ws + (p ? OFF_T1 : OFF_C1);
  gemm64(bufA, W0, p ? tb0 : cb0, 1, bufA, nullptr);      // in-place
  f4v acc[4][4];
  gemm_core(bufA, W1, acc);
  dot_tail(acc, p ? tb1 : cb1, p ? tW2 : cW2,
           p ? tb2[0] : cb2[0], out, m0, n*10 + 8 + p, red);
}

extern "C" void kernel_launch(void* const* d_in, const int* in_sizes, int n_in,
                              void* d_out, int out_size, void* d_ws, size_t ws_size,
                              hipStream_t stream) {
  (void)in_sizes; (void)n_in; (void)out_size; (void)ws_size;
  const float* x   = (const float*)d_in[0];
  const float* oW0 = (const float*)d_in[1];
  const float* ob0 = (const float*)d_in[2];
  const float* oW1 = (const float*)d_in[3];
  const float* ob1 = (const float*)d_in[4];
  const float* oW2 = (const float*)d_in[5];
  const float* ob2 = (const float*)d_in[6];
  const float* cW0 = (const float*)d_in[7];
  const float* cb0 = (const float*)d_in[8];
  const float* cW1 = (const float*)d_in[9];
  const float* cb1 = (const float*)d_in[10];
  const float* cW2 = (const float*)d_in[11];
  const float* cb2 = (const float*)d_in[12];
  const float* tW0 = (const float*)d_in[13];
  const float* tb0 = (const float*)d_in[14];
  const float* tW1 = (const float*)d_in[15];
  const float* tb1 = (const float*)d_in[16];
  const float* tW2 = (const float*)d_in[17];
  const float* tb2 = (const float*)d_in[18];
  const float* aW0 = (const float*)d_in[19];
  const float* ab0 = (const float*)d_in[20];
  const float* aW1 = (const float*)d_in[21];
  const float* ab1 = (const float*)d_in[22];
  const float* aW2 = (const float*)d_in[23];
  const float* ab2 = (const float*)d_in[24];
  unsigned short* ws = (unsigned short*)d_ws;
  float* out = (float*)d_out;

  hipLaunchKernelGGL(prep_kernel, dim3(1728), dim3(256), 0, stream,
                     oW0, oW1, oW2, cW0, cW1, tW0, tW1, aW0, aW1, ws);
  hipLaunchKernelGGL(encoder_kernel, dim3(512), dim3(256), 0, stream,
                     x, ob0, ob1, ob2, ab0, ws);
  hipLaunchKernelGGL(pair_kernel, dim3(256), dim3(256), 0, stream,
                     ws, ab1, aW2, ab2, out);
  hipLaunchKernelGGL(pred_kernel, dim3(1024), dim3(256), 0, stream,
                     ws, cb0, cb1, cW2, cb2, tb0, tb1, tW2, tb2, out);
}

// Round 8
// 181.680 us; speedup vs baseline: 1.8128x; 1.1396x over previous
//
#include <hip/hip_runtime.h>
#include <hip/hip_bf16.h>

// ws layout (in bf16 elements)
#define OFF_O0   0u          // 8 x 256 x 32   (o_W0 transposed, K padded 24->32)
#define OFF_O1   65536u      // 8 x 256 x 256
#define OFF_O2   589824u
#define OFF_C0   1114112u
#define OFF_C1   1179648u
#define OFF_T0   1245184u
#define OFF_T1   1310720u
#define OFF_AL   1376256u    // a_W0[:256]  transposed
#define OFF_AR   1441792u    // a_W0[256:]  transposed
#define OFF_A1   1507328u
#define OFF_ENC  1572864u    // 8 x 4096 x 256 bf16
#define OFF_ALQ  9961472u    // a_l activations, 8 x 4096 x 256
#define OFF_ARQ  18350080u   // a_r + ab0 activations

typedef short s8v __attribute__((ext_vector_type(8)));
typedef float f4v __attribute__((ext_vector_type(4)));

__device__ __forceinline__ unsigned short f2bf(float f) {
  unsigned u = __float_as_uint(f);
  unsigned r = (u + 0x7FFFu + ((u >> 16) & 1u)) >> 16;
  return (unsigned short)r;
}
__device__ __forceinline__ float bf2f(unsigned short h) {
  return __uint_as_float(((unsigned)h) << 16);
}

// ---------- BM=64, 256-thread (4-wave) helpers (encoder / pred) ----------
__device__ __forceinline__ void gemm_epilogue(
    f4v acc[4][4], const float* bias, int act,
    unsigned short* outb, unsigned short* gout)
{
  int lane = threadIdx.x & 63;
  int w    = threadIdx.x >> 6;
  int lr = lane & 15, kh = lane >> 4;
  if (outb) __syncthreads();
  #pragma unroll
  for (int nt = 0; nt < 4; nt++) {
    int col = w*64 + nt*16 + lr;
    float bv = bias ? bias[col] : 0.0f;
    #pragma unroll
    for (int mt = 0; mt < 4; mt++) {
      #pragma unroll
      for (int i = 0; i < 4; i++) {
        int row = mt*16 + kh*4 + i;            // C/D: col=lane&15, row=(lane>>4)*4+reg
        float v = acc[mt][nt][i] + bv;
        if (act) v = fmaxf(v, 0.0f);
        unsigned short hh = f2bf(v);
        if (outb) {
          int bofs = (2*col) ^ ((row & 7) << 4);  // XOR swizzle (G4)
          *(unsigned short*)((char*)outb + row*512 + bofs) = hh;
        }
        if (gout) gout[row*256 + col] = hh;
      }
    }
  }
  if (outb) __syncthreads();
}

__device__ __forceinline__ void gemm_core(
    const unsigned short* inb, const unsigned short* __restrict__ wt,
    f4v acc[4][4])
{
  int lane = threadIdx.x & 63;
  int w    = threadIdx.x >> 6;
  int lr = lane & 15, kh = lane >> 4;
  #pragma unroll
  for (int a = 0; a < 4; a++)
    #pragma unroll
    for (int b = 0; b < 4; b++) acc[a][b] = (f4v){0.f,0.f,0.f,0.f};
  #pragma unroll
  for (int k0 = 0; k0 < 256; k0 += 32) {
    s8v bfrag[4];
    #pragma unroll
    for (int nt = 0; nt < 4; nt++)
      bfrag[nt] = *(const s8v*)(wt + (w*64 + nt*16 + lr)*256 + k0 + kh*8);
    #pragma unroll
    for (int mt = 0; mt < 4; mt++) {
      int row = mt*16 + lr;
      int bofs = (2*k0 + kh*16) ^ ((row & 7) << 4);
      s8v afrag = *(const s8v*)((const char*)inb + row*512 + bofs);
      #pragma unroll
      for (int nt = 0; nt < 4; nt++)
        acc[mt][nt] = __builtin_amdgcn_mfma_f32_16x16x32_bf16(afrag, bfrag[nt], acc[mt][nt], 0, 0, 0);
    }
  }
}

__device__ __forceinline__ void gemm64(
    const unsigned short* inb, const unsigned short* __restrict__ wt,
    const float* bias, int act, unsigned short* outb, unsigned short* gout)
{
  f4v acc[4][4];
  gemm_core(inb, wt, acc);
  gemm_epilogue(acc, bias, act, outb, gout);
}

// fused relu(acc+b1).w2 dot + sigmoid (BM=64, 4 waves)
__device__ __forceinline__ void dot_tail(
    f4v acc[4][4], const float* __restrict__ bias,
    const float* __restrict__ w2, float b2,
    float* __restrict__ out, int m0, int offs, float* red)
{
  int lane = threadIdx.x & 63;
  int w    = threadIdx.x >> 6;
  int lr = lane & 15, kh = lane >> 4;
  float w2v[4], bv[4];
  #pragma unroll
  for (int nt = 0; nt < 4; nt++) {
    int col = w*64 + nt*16 + lr;
    w2v[nt] = w2[col];
    bv[nt]  = bias[col];
  }
  #pragma unroll
  for (int mt = 0; mt < 4; mt++) {
    #pragma unroll
    for (int i = 0; i < 4; i++) {
      float s = 0.0f;
      #pragma unroll
      for (int nt = 0; nt < 4; nt++)
        s += fmaxf(acc[mt][nt][i] + bv[nt], 0.0f) * w2v[nt];
      s += __shfl_xor(s, 1);
      s += __shfl_xor(s, 2);
      s += __shfl_xor(s, 4);
      s += __shfl_xor(s, 8);
      if (lr == 0) red[(mt*16 + kh*4 + i)*4 + w] = s;
    }
  }
  __syncthreads();
  if (threadIdx.x < 64) {
    int row = threadIdx.x;
    float s = red[row*4] + red[row*4+1] + red[row*4+2] + red[row*4+3];
    out[(m0 + row)*80 + offs] = 1.0f / (1.0f + __expf(-s - b2));
  }
}

// layer 0: 64x32 (plain LDS) @ WT0 [256][32]; relu
__device__ __forceinline__ void gemm_x(
    const unsigned short* xb, const unsigned short* __restrict__ wt,
    const float* bias, unsigned short* outb)
{
  int lane = threadIdx.x & 63;
  int w    = threadIdx.x >> 6;
  int lr = lane & 15, kh = lane >> 4;
  f4v acc[4][4];
  #pragma unroll
  for (int a = 0; a < 4; a++)
    #pragma unroll
    for (int b = 0; b < 4; b++) acc[a][b] = (f4v){0.f,0.f,0.f,0.f};

  s8v bfrag[4];
  #pragma unroll
  for (int nt = 0; nt < 4; nt++)
    bfrag[nt] = *(const s8v*)(wt + (w*64 + nt*16 + lr)*32 + kh*8);
  #pragma unroll
  for (int mt = 0; mt < 4; mt++) {
    s8v afrag = *(const s8v*)(xb + (mt*16 + lr)*32 + kh*8);
    #pragma unroll
    for (int nt = 0; nt < 4; nt++)
      acc[mt][nt] = __builtin_amdgcn_mfma_f32_16x16x32_bf16(afrag, bfrag[nt], acc[mt][nt], 0, 0, 0);
  }
  gemm_epilogue(acc, bias, 1, outb, nullptr);
}

// ---------------- weight prep: fp32 -> bf16, transposed to [n][k] -------
__global__ __launch_bounds__(256) void prep_kernel(
    const float* __restrict__ oW0, const float* __restrict__ oW1,
    const float* __restrict__ oW2, const float* __restrict__ cW0,
    const float* __restrict__ cW1, const float* __restrict__ tW0,
    const float* __restrict__ tW1, const float* __restrict__ aW0,
    const float* __restrict__ aW1, unsigned short* __restrict__ ws)
{
  __shared__ float t[32][33];
  int b = blockIdx.x;
  if (b < 1472) {                       // 23 matrices of 256x256, 64 tiles each
    int m = b >> 6, tile = b & 63;
    const float* src; unsigned short* dst;
    if      (m < 8)  { src = oW1 + m*65536;       dst = ws + OFF_O1 + m*65536; }
    else if (m < 16) { src = oW2 + (m-8)*65536;   dst = ws + OFF_O2 + (m-8)*65536; }
    else if (m == 16){ src = cW0;                 dst = ws + OFF_C0; }
    else if (m == 17){ src = cW1;                 dst = ws + OFF_C1; }
    else if (m == 18){ src = tW0;                 dst = ws + OFF_T0; }
    else if (m == 19){ src = tW1;                 dst = ws + OFF_T1; }
    else if (m == 20){ src = aW1;                 dst = ws + OFF_A1; }
    else if (m == 21){ src = aW0;                 dst = ws + OFF_AL; }
    else             { src = aW0 + 65536;         dst = ws + OFF_AR; }
    int kt = tile & 7, nt = tile >> 3;
    int tx = threadIdx.x & 31, ty = threadIdx.x >> 5;
    #pragma unroll
    for (int r = 0; r < 4; r++) {
      int ky = ty*4 + r;
      t[ky][tx] = src[(kt*32 + ky)*256 + nt*32 + tx];
    }
    __syncthreads();
    #pragma unroll
    for (int r = 0; r < 4; r++) {
      int ny = ty*4 + r;
      dst[(nt*32 + ny)*256 + kt*32 + tx] = f2bf(t[tx][ny]);
    }
  } else {                              // o_W0: (8,24,256) -> (8,256,32) padded
    int idx = (b - 1472)*256 + threadIdx.x;
    int k = idx & 31, n2 = (idx >> 5) & 255, nb = idx >> 13;
    float v = (k < 24) ? oW0[(nb*24 + k)*256 + n2] : 0.0f;
    ws[OFF_O0 + idx] = f2bf(v);
  }
}

// ---------------- object encoders + a_l / (a_r + b0) projections ---------
__global__ __launch_bounds__(256) void encoder_kernel(
    const float* __restrict__ x,
    const float* __restrict__ ob0, const float* __restrict__ ob1,
    const float* __restrict__ ob2, const float* __restrict__ ab0,
    unsigned short* __restrict__ ws)
{
  __shared__ unsigned short buf[64*256];   // 32 KB, chained in-place
  __shared__ unsigned short xb[64*32];     // 4 KB
  int n  = blockIdx.x >> 6;
  int m0 = (blockIdx.x & 63) * 64;

  for (int t = threadIdx.x; t < 64*32; t += 256) {
    int row = t >> 5, c = t & 31;
    xb[t] = f2bf(c < 24 ? x[(m0 + row)*24 + c] : 0.0f);
  }
  __syncthreads();
  gemm_x (xb,  ws + OFF_O0 + n*8192,  ob0 + n*256, buf);
  gemm64 (buf, ws + OFF_O1 + n*65536, ob1 + n*256, 1, buf, nullptr);
  gemm64 (buf, ws + OFF_O2 + n*65536, ob2 + n*256, 0, buf,
          ws + OFF_ENC + (unsigned)(n*4096 + m0)*256);
  gemm64 (buf, ws + OFF_AL, nullptr, 0, nullptr,
          ws + OFF_ALQ + (unsigned)(n*4096 + m0)*256);
  gemm64 (buf, ws + OFF_AR, ab0, 0, nullptr,                 // fold a_b0 here
          ws + OFF_ARQ + (unsigned)(n*4096 + m0)*256);
}

// ---------------- AonB: BM=64, 512 thr (2wm x 4wn), j-loop, dbuf ---------
// 512 blocks x 512 thr; LDS 66.5 KB -> 2 blocks/CU = 4 waves/SIMD.
// W1 streamed from L2 (__restrict__); ph double-buffered; R prefetched to
// regs (L reloads hit L1); ONE barrier per item (red dbuf'd by j-parity).
__global__ __launch_bounds__(512) void pair_kernel(
    const unsigned short* __restrict__ ws,
    const float* __restrict__ ab1, const float* __restrict__ aW2,
    const float* __restrict__ ab2, float* __restrict__ out)
{
  __shared__ unsigned short ph[2][64*256];   // 2 x 32 KB
  __shared__ float red[2][256];              // 2 KB
  int b = blockIdx.x;
  int i = b >> 6, chunk = b & 63;            // R-sharers (same chunk) keep
  int m0 = chunk * 64;                       // same b%8 -> same XCD
  const unsigned short* Lp    = ws + OFF_ALQ + ((unsigned)i*4096u + m0)*256u;
  const unsigned short* Rbase = ws + OFF_ARQ + (unsigned)m0*256u;
  const unsigned short* wt    = ws + OFF_A1;

  int tid  = threadIdx.x;
  int lane = tid & 63, w = tid >> 6;         // w 0..7
  int wm = w >> 2, wn = w & 3;
  int lr = lane & 15, kh = lane >> 4;

  // staging slots: 64 rows x 32 chunks, 4 per thread
  int srow[4], sc8[4];
  #pragma unroll
  for (int q = 0; q < 4; q++) {
    int idx = q*512 + tid;
    srow[q] = idx >> 5; sc8[q] = idx & 31;
  }

  float w2v[4], bv[4];
  #pragma unroll
  for (int nt = 0; nt < 4; nt++) {
    int col = wn*64 + nt*16 + lr;
    w2v[nt] = aW2[col];
    bv[nt]  = ab1[col];
  }
  float b2 = ab2[0];

  // prologue: construct j=0 into ph[0]
  #pragma unroll
  for (int q = 0; q < 4; q++) {
    unsigned off = (unsigned)srow[q]*256u + sc8[q]*8;
    s8v l8 = *(const s8v*)(Lp + off);
    s8v r8 = *(const s8v*)(Rbase + off);
    s8v o8;
    #pragma unroll
    for (int e = 0; e < 8; e++) {
      float v = bf2f((unsigned short)l8[e]) + bf2f((unsigned short)r8[e]);
      o8[e] = (short)f2bf(fmaxf(v, 0.0f));
    }
    *(s8v*)((char*)ph[0] + srow[q]*512 + ((sc8[q]*16) ^ ((srow[q] & 7) << 4))) = o8;
  }
  __syncthreads();

  int c = 0;
  for (int j = 0; j < 8; j++) {
    // prefetch R(j+1) into regs; L reloaded at construct (L1-hot)
    s8v Rr[4];
    if (j < 7) {
      const unsigned short* Rp = Rbase + (unsigned)(j+1)*(4096u*256u);
      #pragma unroll
      for (int q = 0; q < 4; q++)
        Rr[q] = *(const s8v*)(Rp + (unsigned)srow[q]*256u + sc8[q]*8);
    }
    // GEMM(j): 64x256 @ 256x256 (A from ph[c], B streamed from L2)
    f4v acc[2][4];
    #pragma unroll
    for (int a = 0; a < 2; a++)
      #pragma unroll
      for (int cc = 0; cc < 4; cc++) acc[a][cc] = (f4v){0.f,0.f,0.f,0.f};
    #pragma unroll
    for (int k0 = 0; k0 < 256; k0 += 32) {
      s8v bfrag[4];
      #pragma unroll
      for (int nt = 0; nt < 4; nt++)
        bfrag[nt] = *(const s8v*)(wt + (wn*64 + nt*16 + lr)*256 + k0 + kh*8);
      #pragma unroll
      for (int mt = 0; mt < 2; mt++) {
        int row = wm*32 + mt*16 + lr;
        int bofs = (2*k0 + kh*16) ^ ((row & 7) << 4);
        s8v afrag = *(const s8v*)((const char*)ph[c] + row*512 + bofs);
        #pragma unroll
        for (int nt = 0; nt < 4; nt++)
          acc[mt][nt] = __builtin_amdgcn_mfma_f32_16x16x32_bf16(afrag, bfrag[nt], acc[mt][nt], 0, 0, 0);
      }
    }
    // construct PH(j+1) into the other half (ph[c^1] fully read at j-1)
    if (j < 7) {
      #pragma unroll
      for (int q = 0; q < 4; q++) {
        s8v l8 = *(const s8v*)(Lp + (unsigned)srow[q]*256u + sc8[q]*8);
        s8v o8;
        #pragma unroll
        for (int e = 0; e < 8; e++) {
          float v = bf2f((unsigned short)l8[e]) + bf2f((unsigned short)Rr[q][e]);
          o8[e] = (short)f2bf(fmaxf(v, 0.0f));
        }
        *(s8v*)((char*)ph[c ^ 1] + srow[q]*512 + ((sc8[q]*16) ^ ((srow[q] & 7) << 4))) = o8;
      }
    }
    // fused dot -> red[c]
    #pragma unroll
    for (int mt = 0; mt < 2; mt++) {
      #pragma unroll
      for (int ii = 0; ii < 4; ii++) {
        float s = 0.0f;
        #pragma unroll
        for (int nt = 0; nt < 4; nt++)
          s += fmaxf(acc[mt][nt][ii] + bv[nt], 0.0f) * w2v[nt];
        s += __shfl_xor(s, 1);
        s += __shfl_xor(s, 2);
        s += __shfl_xor(s, 4);
        s += __shfl_xor(s, 8);
        if (lr == 0) red[c][(wm*32 + mt*16 + kh*4 + ii)*4 + wn] = s;
      }
    }
    __syncthreads();   // guards: ph[c] reads done, ph[c^1] ready, red[c] ready
    if (tid < 64) {
      float s = red[c][tid*4] + red[c][tid*4+1] + red[c][tid*4+2] + red[c][tid*4+3];
      out[(m0 + tid)*80 + i*10 + j] = 1.0f / (1.0f + __expf(-s - b2));
    }
    c ^= 1;
  }
}

// ---------------- clear / ontable predicates (round-2 form) --------------
__global__ __launch_bounds__(256) void pred_kernel(
    const unsigned short* __restrict__ ws,
    const float* __restrict__ cb0, const float* __restrict__ cb1,
    const float* __restrict__ cW2, const float* __restrict__ cb2,
    const float* __restrict__ tb0, const float* __restrict__ tb1,
    const float* __restrict__ tW2, const float* __restrict__ tb2,
    float* __restrict__ out)
{
  __shared__ unsigned short bufA[64*256];  // 32 KB
  __shared__ float red[256];
  int b  = blockIdx.x;
  int p  = b >> 9;            // 0=clear, 1=ontable
  int n  = (b >> 6) & 7;
  int m0 = (b & 63) * 64;
  const unsigned short* encp = ws + OFF_ENC + (unsigned)(n*4096 + m0)*256;
  for (int t = threadIdx.x; t < 64*32; t += 256) {
    int row = t >> 5, chunk = t & 31;
    s8v v = *(const s8v*)(encp + row*256 + chunk*8);
    int bofs = (chunk*16) ^ ((row & 7) << 4);
    *(s8v*)((char*)bufA + row*512 + bofs) = v;
  }
  __syncthreads();
  const unsigned short* W0 = ws + (p ? OFF_T0 : OFF_C0);
  const unsigned short* W1 = ws + (p ? OFF_T1 : OFF_C1);
  gemm64(bufA, W0, p ? tb0 : cb0, 1, bufA, nullptr);      // in-place
  f4v acc[4][4];
  gemm_core(bufA, W1, acc);
  dot_tail(acc, p ? tb1 : cb1, p ? tW2 : cW2,
           p ? tb2[0] : cb2[0], out, m0, n*10 + 8 + p, red);
}

extern "C" void kernel_launch(void* const* d_in, const int* in_sizes, int n_in,
                              void* d_out, int out_size, void* d_ws, size_t ws_size,
                              hipStream_t stream) {
  (void)in_sizes; (void)n_in; (void)out_size; (void)ws_size;
  const float* x   = (const float*)d_in[0];
  const float* oW0 = (const float*)d_in[1];
  const float* ob0 = (const float*)d_in[2];
  const float* oW1 = (const float*)d_in[3];
  const float* ob1 = (const float*)d_in[4];
  const float* oW2 = (const float*)d_in[5];
  const float* ob2 = (const float*)d_in[6];
  const float* cW0 = (const float*)d_in[7];
  const float* cb0 = (const float*)d_in[8];
  const float* cW1 = (const float*)d_in[9];
  const float* cb1 = (const float*)d_in[10];
  const float* cW2 = (const float*)d_in[11];
  const float* cb2 = (const float*)d_in[12];
  const float* tW0 = (const float*)d_in[13];
  const float* tb0 = (const float*)d_in[14];
  const float* tW1 = (const float*)d_in[15];
  const float* tb1 = (const float*)d_in[16];
  const float* tW2 = (const float*)d_in[17];
  const float* tb2 = (const float*)d_in[18];
  const float* aW0 = (const float*)d_in[19];
  const float* ab0 = (const float*)d_in[20];
  const float* aW1 = (const float*)d_in[21];
  const float* ab1 = (const float*)d_in[22];
  const float* aW2 = (const float*)d_in[23];
  const float* ab2 = (const float*)d_in[24];
  unsigned short* ws = (unsigned short*)d_ws;
  float* out = (float*)d_out;

  hipLaunchKernelGGL(prep_kernel, dim3(1728), dim3(256), 0, stream,
                     oW0, oW1, oW2, cW0, cW1, tW0, tW1, aW0, aW1, ws);
  hipLaunchKernelGGL(encoder_kernel, dim3(512), dim3(256), 0, stream,
                     x, ob0, ob1, ob2, ab0, ws);
  hipLaunchKernelGGL(pair_kernel, dim3(512), dim3(512), 0, stream,
                     ws, ab1, aW2, ab2, out);
  hipLaunchKernelGGL(pred_kernel, dim3(1024), dim3(256), 0, stream,
                     ws, cb0, cb1, cW2, cb2, tb0, tb1, tW2, tb2, out);
}